// Round 5
// baseline (103.794 us; speedup 1.0000x reference)
//
#include <hip/hip_runtime.h>
#include <hip/hip_bf16.h>

#define LSEQ   200
#define LPAD   208
#define EMB    32
#define TDIM   128
#define COND   160
#define ROWS   321
#define MASK_T 48
#define LL_LDB 80      // LL row stride bytes (64B data + 16B pad)

typedef __attribute__((ext_vector_type(8))) short  short8;
typedef __attribute__((ext_vector_type(4))) float  f32x4;

__device__ __forceinline__ float bf2f(unsigned short u) {
    union { unsigned int i; float f; } v; v.i = ((unsigned int)u) << 16; return v.f;
}
__device__ __forceinline__ unsigned int f2bf(float f) {
    union { float f; unsigned int i; } v; v.f = f;
    unsigned int x = v.i;
    return ((x + 0x7fffu + ((x >> 16) & 1u)) >> 16);   // RNE, low 16
}
__device__ __forceinline__ unsigned int pack2(float lo, float hi) {
    return f2bf(lo) | (f2bf(hi) << 16);
}
__device__ __forceinline__ short8 pack8(float4 a, float4 b) {
    union { short8 s; unsigned int u[4]; } r;
    r.u[0] = pack2(a.x, a.y); r.u[1] = pack2(a.z, a.w);
    r.u[2] = pack2(b.x, b.y); r.u[3] = pack2(b.z, b.w);
    return r.s;
}

// 16-lane (DPP-row) sum reduction on the VALU pipe — no DS ops.
template<int CTRL>
__device__ __forceinline__ float dpp_add(float v) {
    const int x = __builtin_amdgcn_update_dpp(0, __float_as_int(v), CTRL, 0xf, 0xf, true);
    return v + __int_as_float(x);
}
__device__ __forceinline__ float red16(float v) {
    v = dpp_add<0x128>(v);   // row_ror:8
    v = dpp_add<0x124>(v);   // row_ror:4
    v = dpp_add<0x122>(v);   // row_ror:2
    v = dpp_add<0x121>(v);   // row_ror:1
    return v;
}

// ---- prep: tables (blocks 0..48) + optional loc_emb bf16 conversion ----
__global__ void prep(const float* __restrict__ w1, const float* __restrict__ w2,
                     const float* __restrict__ loc_emb,
                     unsigned short* __restrict__ te_tab,   // [49][128] bf16
                     float*          __restrict__ T1t,      // [160][52] fp32 (t-major-inner)
                     unsigned short* __restrict__ te_t,     // [128][56] bf16
                     unsigned short* __restrict__ T2p,      // [49][256] bf16 permuted
                     unsigned short* __restrict__ locb,     // [100000][32] bf16
                     int do_locb) {
    const int bid = blockIdx.x, tid = threadIdx.x;
    if (bid < 49) {
        __shared__ float te128[TDIM];
        const int t = bid;
        if (tid < 64) {
            const float dv = __expf(-0.14391156f * (float)tid);  // 10000^(-tid/64)
            const float a  = (float)t * dv;
            const float s  = __sinf(a), c = __cosf(a);
            te128[2 * tid] = s; te128[2 * tid + 1] = c;
            ((unsigned int*)te_tab)[t * 64 + tid] = pack2(s, c);
        }
        __syncthreads();
        if (tid < COND) {
            float s1 = 0.0f, s2 = 0.0f;
            const float* w1r = w1 + tid * COND + EMB;
            const float* w2r = w2 + tid * COND + EMB;
            #pragma unroll 8
            for (int j = 0; j < TDIM; ++j) {
                s1 = fmaf(te128[j], w1r[j], s1);
                s2 = fmaf(te128[j], w2r[j], s2);
            }
            if (t == MASK_T) { s1 = 0.0f; s2 = 0.0f; }
            T1t[tid * 52 + t] = s1;
            T2p[t * 256 + 4 * (tid & 63) + (tid >> 6)] = (unsigned short)f2bf(s2);
        } else {
            const int idx  = tid - COND;                      // 96 zero slots
            const int slot = (idx < 64) ? (4 * idx + 3) : (4 * (32 + idx - 64) + 2);
            T2p[t * 256 + slot] = 0;
        }
        if (tid < TDIM) te_t[tid * 56 + t] = (unsigned short)f2bf(te128[tid]);
        if (t == 0) {   // zero the pad slots (d_ws is poisoned between runs)
            for (int i = tid; i < TDIM * 7; i += 256) te_t[(i / 7) * 56 + 49 + (i % 7)] = 0;
            for (int i = tid; i < COND * 3; i += 256) T1t[(i / 3) * 52 + 49 + (i % 3)] = 0.0f;
        }
    } else if (do_locb) {
        const int i = (bid - 49) * 256 + tid;                 // 800,000 float4
        if (i < 800000) {
            const float4 v = ((const float4*)loc_emb)[i];
            ((uint2*)locb)[i] = make_uint2(pack2(v.x, v.y), pack2(v.z, v.w));
        }
    }
}

template<bool LOCB>
__global__ __launch_bounds__(256, 6)
void fused_cond(const int*   __restrict__ tp,
                const int*   __restrict__ loc,
                const float* __restrict__ emb,
                const int*   __restrict__ st,        // [B][L][2]
                const float* __restrict__ loc_emb,   // [V][32] fp32
                const unsigned short* __restrict__ locb,   // [V][32] bf16 (if LOCB)
                const float* __restrict__ noise,
                const int*   __restrict__ tstep,
                const float* __restrict__ w1,        // fp32 (cols 0..31 used)
                const float* __restrict__ w2,        // fp32 (cols 0..31 used)
                const unsigned short* __restrict__ te_tab,
                const float* __restrict__ T1t,       // [160][52]
                const unsigned short* __restrict__ te_t,  // [128][56]
                const unsigned short* __restrict__ T2p,   // [49][256]
                const float* __restrict__ b2,
                const float* __restrict__ wc,
                const float* __restrict__ alpha_hat,
                float* __restrict__ out)             // [B][321][32]
{
    __shared__ __attribute__((aligned(16))) unsigned char LL[LPAD * LL_LDB]; // 16,640
    __shared__ __attribute__((aligned(16))) float score4[4 * LPAD];          // 3,328
    __shared__ float score[LPAD];
    __shared__ float side[COND];
    __shared__ float m1s[COND];
    __shared__ float u160[COND];
    __shared__ float mloc[EMB];
    __shared__ float sb[56];
    __shared__ float cntf[52];
    __shared__ unsigned int cnt[52];
    __shared__ __attribute__((aligned(8))) unsigned short ttr[LPAD];

    const int b   = blockIdx.x;
    const int tid = threadIdx.x;
    float* outb = out + (size_t)b * (ROWS * EMB);
    float4* ob4 = (float4*)outb;

    // ---- early per-lane loads (no deps): B-fragments + wc ----
    const int wv = tid >> 6, lane = tid & 63, lc = lane & 15, lg = lane >> 4;
    const int cbase = wv * 16 + lc;            // [0,64)
    const bool nn3 = (wv < 2);                 // third tile exists
    short8 bf0, bf1, bf2v = short8{0,0,0,0,0,0,0,0};
    {
        const float4* r0 = (const float4*)(w2 + (size_t)cbase * COND + lg * 8);
        bf0 = pack8(r0[0], r0[1]);
        const float4* r1 = (const float4*)(w2 + (size_t)(cbase + 64) * COND + lg * 8);
        bf1 = pack8(r1[0], r1[1]);
        if (nn3) {
            const float4* r2 = (const float4*)(w2 + (size_t)(cbase + 128) * COND + lg * 8);
            bf2v = pack8(r2[0], r2[1]);
        }
    }
    const float wc0 = wc[cbase];
    const float wc1 = wc[cbase + 64];
    const float wc2 = nn3 ? wc[cbase + 128] : 0.0f;

    // ---- P0: init + side + noisy row ----
    if (tid < 56)  sb[tid] = 0.0f;
    if (tid < 52)  cnt[tid] = 0u;
    if (tid >= 64 && tid < 96) mloc[tid - 64] = 0.0f;
    if (tid < TDIM) {
        side[tid] = bf2f(te_tab[tp[b] * TDIM + tid]);
    } else if (tid < COND) {
        side[tid] = loc_emb[(size_t)(loc[b] - 1) * EMB + (tid - TDIM)];
    } else if (tid < COND + EMB) {
        const int   e = tid - COND;
        const float a = alpha_hat[tstep[b]];
        outb[320 * EMB + e] = sqrtf(a) * emb[b * EMB + e]
                            + sqrtf(1.0f - a) * noise[b * EMB + e];
    }
    __syncthreads();

    // ---- P1: ST rows + ttr/cnt + LL staging ----
    for (int i4 = tid; i4 < COND * 8; i4 += 256) {
        const float v = side[i4 >> 3];
        ob4[i4] = make_float4(v, v, v, v);
    }
    if (tid < LPAD) {
        unsigned short t16 = 0;
        if (tid < LSEQ) {
            const int tt = ((const int2*)st)[b * LSEQ + tid].y;
            t16 = (unsigned short)tt;
            if (tt != MASK_T) atomicAdd(&cnt[tt], 1u);
        }
        ttr[tid] = t16;
    }
    for (int ci = tid; ci < LPAD * 4; ci += 256) {
        const int l = ci >> 2, q = ci & 3;
        uint4 val = make_uint4(0, 0, 0, 0);
        if (l < LSEQ) {
            const int s = ((const int2*)st)[b * LSEQ + l].x;
            if (LOCB) {
                val = ((const uint4*)(locb + (size_t)(s - 1) * EMB))[q];
            } else {
                const float4* lr = (const float4*)(loc_emb + (size_t)(s - 1) * EMB + q * 8);
                const float4 v0 = lr[0], v1 = lr[1];
                val = make_uint4(pack2(v0.x, v0.y), pack2(v0.z, v0.w),
                                 pack2(v1.x, v1.y), pack2(v1.z, v1.w));
            }
        }
        *(uint4*)(LL + l * LL_LDB + q * 16) = val;
    }
    __syncthreads();

    // ---- P2: mloc column sums + cnt->float ----
    {
        const int c = tid & 31, g = tid >> 5;            // 8 groups x 25 rows
        const unsigned char* p = LL + g * 25 * LL_LDB + 2 * c;
        float s = 0.0f;
        #pragma unroll 5
        for (int l = 0; l < 25; ++l)
            s += bf2f(*(const unsigned short*)(p + l * LL_LDB));
        atomicAdd(&mloc[c], s);
    }
    if (tid < 52) cntf[tid] = (tid < 49) ? (float)cnt[tid] : 0.0f;
    __syncthreads();

    // ---- P3: m1 = b2 + mloc/200 @ w1[:, :32]^T + cntf @ T1t /200 ----
    if (tid < COND) {
        float m = b2[tid];
        const float4* w1r = (const float4*)(w1 + (size_t)tid * COND);
        #pragma unroll
        for (int j4 = 0; j4 < 8; ++j4) {
            const float4 w4 = w1r[j4];
            m = fmaf(mloc[j4 * 4 + 0] * 0.005f, w4.x, m);
            m = fmaf(mloc[j4 * 4 + 1] * 0.005f, w4.y, m);
            m = fmaf(mloc[j4 * 4 + 2] * 0.005f, w4.z, m);
            m = fmaf(mloc[j4 * 4 + 3] * 0.005f, w4.w, m);
        }
        float mt = 0.0f;
        const float4* t1r = (const float4*)(T1t + tid * 52);
        #pragma unroll
        for (int t4 = 0; t4 < 13; ++t4) {
            const float4 v = t1r[t4];
            mt = fmaf(cntf[t4 * 4 + 0], v.x, mt);
            mt = fmaf(cntf[t4 * 4 + 1], v.y, mt);
            mt = fmaf(cntf[t4 * 4 + 2], v.z, mt);
            mt = fmaf(cntf[t4 * 4 + 3], v.w, mt);
        }
        m1s[tid] = m + mt * 0.005f;
    }
    __syncthreads();

    // ---- P4: MFMA (K=32) + T2p gather + sigmoid + DPP score reduce ----
    const float m10 = m1s[cbase];
    const float m11 = m1s[cbase + 64];
    const float m12 = nn3 ? m1s[cbase + 128] : 0.0f;

    for (int m = 0; m < 13; ++m) {
        const short8 av = *(const short8*)(LL + (m * 16 + lc) * LL_LDB + lg * 16);
        f32x4 a0 = {0,0,0,0}, a1 = {0,0,0,0}, a2 = {0,0,0,0};
        a0 = __builtin_amdgcn_mfma_f32_16x16x32_bf16(av, bf0, a0, 0, 0, 0);
        a1 = __builtin_amdgcn_mfma_f32_16x16x32_bf16(av, bf1, a1, 0, 0, 0);
        if (nn3)
            a2 = __builtin_amdgcn_mfma_f32_16x16x32_bf16(av, bf2v, a2, 0, 0, 0);

        const ushort4 t4 = *(const ushort4*)(ttr + m * 16 + lg * 4);
        f32x4 sc;
        #pragma unroll
        for (int r = 0; r < 4; ++r) {
            const int t = (r == 0) ? t4.x : (r == 1) ? t4.y : (r == 2) ? t4.z : t4.w;
            const ushort4 p = *(const ushort4*)(T2p + t * 256 + 4 * cbase);
            float s = wc0 / (1.0f + __expf(-(a0[r] + m10 + bf2f(p.x))));
            s      += wc1 / (1.0f + __expf(-(a1[r] + m11 + bf2f(p.y))));
            if (nn3)
                s  += wc2 / (1.0f + __expf(-(a2[r] + m12 + bf2f(p.z))));
            sc[r] = red16(s);
        }
        if (lc == 0)
            *(float4*)(score4 + wv * LPAD + m * 16 + lg * 4) =
                make_float4(sc[0], sc[1], sc[2], sc[3]);
    }
    __syncthreads();

    // ---- P5a: combine wave partials + score histogram ----
    if (tid < LPAD) {
        const float s = score4[tid] + score4[LPAD + tid]
                      + score4[2 * LPAD + tid] + score4[3 * LPAD + tid];
        score[tid] = s;
        if (tid < LSEQ) {
            const int tt = ttr[tid];
            if (tt != MASK_T) atomicAdd(&sb[tt], s);
        }
    }
    __syncthreads();

    // ---- P5b: uemb (te half via sb table; loc half via score·LL) ----
    if (tid < TDIM) {
        float s = 0.0f;
        const ushort4* tr = (const ushort4*)(te_t + tid * 56);
        #pragma unroll
        for (int t4i = 0; t4i < 14; ++t4i) {
            const ushort4 v = tr[t4i];
            s = fmaf(sb[t4i * 4 + 0], bf2f(v.x), s);
            s = fmaf(sb[t4i * 4 + 1], bf2f(v.y), s);
            s = fmaf(sb[t4i * 4 + 2], bf2f(v.z), s);
            s = fmaf(sb[t4i * 4 + 3], bf2f(v.w), s);
        }
        u160[EMB + tid] = s;
    } else {
        const int idx = tid - 128;                    // 128 workers
        const int col = idx >> 2, grp = idx & 3;      // 32 cols x 4 row-groups
        const unsigned char* p = LL + grp * 50 * LL_LDB + 2 * col;
        const float* sr = score + grp * 50;
        float s = 0.0f;
        #pragma unroll 5
        for (int l = 0; l < 50; ++l)
            s = fmaf(sr[l], bf2f(*(const unsigned short*)(p + l * LL_LDB)), s);
        // quad reduce (lanes idx&3 aligned with lane&3)
        {
            int x = __builtin_amdgcn_update_dpp(0, __float_as_int(s), 0xB1, 0xf, 0xf, true);
            s += __int_as_float(x);                   // quad_perm [1,0,3,2]
            x = __builtin_amdgcn_update_dpp(0, __float_as_int(s), 0x4E, 0xf, 0xf, true);
            s += __int_as_float(x);                   // quad_perm [2,3,0,1]
        }
        if (grp == 0) u160[col] = s;
    }
    __syncthreads();

    // ---- P6: coalesced user_info rows ----
    #pragma unroll
    for (int t = 0; t < 5; ++t) {
        const int i4 = tid + t * 256;
        const float v = u160[i4 >> 3];
        ob4[COND * 8 + i4] = make_float4(v, v, v, v);
    }
}

extern "C" void kernel_launch(void* const* d_in, const int* in_sizes, int n_in,
                              void* d_out, int out_size, void* d_ws, size_t ws_size,
                              hipStream_t stream) {
    const int*   tp        = (const int*)  d_in[0];
    const int*   loc       = (const int*)  d_in[1];
    const float* emb       = (const float*)d_in[2];
    const int*   st        = (const int*)  d_in[3];
    const float* loc_emb   = (const float*)d_in[4];
    const float* noise     = (const float*)d_in[5];
    const int*   tstep     = (const int*)  d_in[6];
    const float* w1        = (const float*)d_in[7];
    const float* w2        = (const float*)d_in[8];
    const float* b2        = (const float*)d_in[9];
    const float* wc        = (const float*)d_in[10];
    const float* alpha_hat = (const float*)d_in[11];
    float* out = (float*)d_out;

    char* ws = (char*)d_ws;
    float*          T1t    = (float*)ws;                          // 33,280 B
    unsigned short* te_tab = (unsigned short*)(ws + 33280);       // 12,544 B
    unsigned short* te_t   = (unsigned short*)(ws + 45824);       // 14,336 B
    unsigned short* T2p    = (unsigned short*)(ws + 60160);       // 25,088 B
    unsigned short* locb   = (unsigned short*)(ws + 85248);       // 6,400,000 B
    const bool use_locb = (ws_size >= (size_t)85248 + 6400000);

    prep<<<use_locb ? 49 + 3125 : 49, 256, 0, stream>>>(
        w1, w2, loc_emb, te_tab, T1t, te_t, T2p, locb, use_locb ? 1 : 0);

    const int nb = in_sizes[0];   // 2048
    if (use_locb)
        fused_cond<true><<<nb, 256, 0, stream>>>(tp, loc, emb, st, loc_emb, locb,
            noise, tstep, w1, w2, te_tab, T1t, te_t, T2p, b2, wc, alpha_hat, out);
    else
        fused_cond<false><<<nb, 256, 0, stream>>>(tp, loc, emb, st, loc_emb, locb,
            noise, tstep, w1, w2, te_tab, T1t, te_t, T2p, b2, wc, alpha_hat, out);
}

// Round 6
// 75.826 us; speedup vs baseline: 1.3688x; 1.3688x over previous
//
#include <hip/hip_runtime.h>
#include <hip/hip_bf16.h>

#define LSEQ   200
#define LPAD   208
#define EMB    32
#define TDIM   128
#define COND   160
#define ROWS   321
#define MASK_T 48

typedef __attribute__((ext_vector_type(8))) short  short8;
typedef __attribute__((ext_vector_type(4))) float  f32x4;

#define WAIT_LGKM() asm volatile("s_waitcnt lgkmcnt(0)" ::: "memory")

__device__ __forceinline__ float bf2f(unsigned short u) {
    union { unsigned int i; float f; } v; v.i = ((unsigned int)u) << 16; return v.f;
}
__device__ __forceinline__ unsigned int f2bf(float f) {
    union { float f; unsigned int i; } v; v.f = f;
    unsigned int x = v.i;
    return ((x + 0x7fffu + ((x >> 16) & 1u)) >> 16);   // RNE, low 16
}
__device__ __forceinline__ unsigned int pack2(float lo, float hi) {
    return f2bf(lo) | (f2bf(hi) << 16);
}
__device__ __forceinline__ short8 pack8(f32x4 a, f32x4 b) {
    union { short8 s; unsigned int u[4]; } r;
    r.u[0] = pack2(a[0], a[1]); r.u[1] = pack2(a[2], a[3]);
    r.u[2] = pack2(b[0], b[1]); r.u[3] = pack2(b[2], b[3]);
    return r.s;
}

// 16-lane (DPP row) sum — VALU pipe only.
template<int CTRL>
__device__ __forceinline__ float dpp_add(float v) {
    const int x = __builtin_amdgcn_update_dpp(0, __float_as_int(v), CTRL, 0xf, 0xf, true);
    return v + __int_as_float(x);
}
__device__ __forceinline__ float red16(float v) {
    v = dpp_add<0x128>(v);   // row_ror:8
    v = dpp_add<0x124>(v);   // row_ror:4
    v = dpp_add<0x122>(v);   // row_ror:2
    v = dpp_add<0x121>(v);   // row_ror:1
    return v;
}

// ---- prep (49 blocks): te_tab[49][128] bf16; T1t[160][52] f32; te_t[128][52] bf16;
//      T2w[49][16][12] bf16 (T2w[t][lc][tile] = T2[t][tile*16+lc]); mask row t==48 -> 0.
__global__ void prep(const float* __restrict__ w1, const float* __restrict__ w2,
                     unsigned short* __restrict__ te_tab, float* __restrict__ T1t,
                     unsigned short* __restrict__ te_t, unsigned short* __restrict__ T2w) {
    __shared__ float te128[TDIM];
    const int t = blockIdx.x, tid = threadIdx.x;
    if (tid < 64) {
        const float dv = __expf(-0.14391156f * (float)tid);  // 10000^(-tid/64)
        const float a  = (float)t * dv;
        const float s  = __sinf(a), c = __cosf(a);
        te128[2 * tid] = s; te128[2 * tid + 1] = c;
        ((unsigned int*)te_tab)[t * 64 + tid] = pack2(s, c);
    }
    __syncthreads();
    if (tid < COND) {
        float s1 = 0.0f, s2 = 0.0f;
        const float* w1r = w1 + tid * COND + EMB;
        const float* w2r = w2 + tid * COND + EMB;
        #pragma unroll 8
        for (int j = 0; j < TDIM; ++j) {
            s1 = fmaf(te128[j], w1r[j], s1);
            s2 = fmaf(te128[j], w2r[j], s2);
        }
        if (t == MASK_T) { s1 = 0.0f; s2 = 0.0f; }
        T1t[tid * 52 + t] = s1;
        T2w[t * 192 + (tid & 15) * 12 + (tid >> 4)] = (unsigned short)f2bf(s2);
    }
    if (tid < TDIM) te_t[tid * 52 + t] = (unsigned short)f2bf(te128[tid]);
}

// ---- main: one wave per batch, zero block barriers ----
__global__ __launch_bounds__(256)
void fused_wave(const int*   __restrict__ tp,
                const int*   __restrict__ loc,
                const float* __restrict__ emb,
                const int*   __restrict__ st,        // [B][L][2]
                const float* __restrict__ loc_emb,   // [V][32] fp32
                const float* __restrict__ noise,
                const int*   __restrict__ tstep,
                const float* __restrict__ w1,        // fp32 (cols 0..31 used here)
                const float* __restrict__ w2,        // fp32 (cols 0..31 used here)
                const unsigned short* __restrict__ te_tab,
                const float* __restrict__ T1t,       // [160][52]
                const unsigned short* __restrict__ te_t,   // [128][52]
                const unsigned short* __restrict__ T2w,    // [49][16][12]
                const float* __restrict__ b2,
                const float* __restrict__ wc,
                const float* __restrict__ alpha_hat,
                float* __restrict__ out, int nb)     // [B][321][32]
{
    __shared__ unsigned short ttr[4][LPAD];
    __shared__ int            ssr[4][LPAD];
    __shared__ float          scoreA[4][LPAD];
    __shared__ float          su[4][320];    // [side(160) | uemb(160)]
    __shared__ float          mloc[4][32];
    __shared__ float          m1A[4][COND];
    __shared__ float          cntA[4][52];
    __shared__ float          sbA[4][52];

    const int tid  = threadIdx.x;
    const int w    = tid >> 6, lane = tid & 63;
    const int b    = blockIdx.x * 4 + w;
    if (b >= nb) return;
    const int lc = lane & 15, lg = lane >> 4;

    unsigned short* ttrW = ttr[w];
    int*   ssrW = ssr[w];
    float* scoreW = scoreA[w];
    float* suW  = su[w];
    float* mlocW = mloc[w];
    float* m1W  = m1A[w];
    float* cntW = cntA[w];
    float* sbW  = sbA[w];
    float* outb = out + (size_t)b * (ROWS * EMB);

    // ---- P0: zero bins; side row; noisy row ----
    if (lane < 52) { cntW[lane] = 0.0f; sbW[lane] = 0.0f; }
    if (lane < 32) {
        const ushort4 tv = *(const ushort4*)(te_tab + tp[b] * TDIM + lane * 4);
        f32x4 s4 = { bf2f(tv.x), bf2f(tv.y), bf2f(tv.z), bf2f(tv.w) };
        *(f32x4*)(suW + lane * 4) = s4;
    } else if (lane < 40) {
        const f32x4 lv = *(const f32x4*)(loc_emb + (size_t)(loc[b] - 1) * EMB + (lane - 32) * 4);
        *(f32x4*)(suW + 128 + (lane - 32) * 4) = lv;
    } else if (lane < 48) {
        const int e4 = lane - 40;
        const float a = alpha_hat[tstep[b]];
        const float sa = sqrtf(a), sn = sqrtf(1.0f - a);
        const f32x4 ev = *(const f32x4*)(emb + (size_t)b * EMB + e4 * 4);
        const f32x4 nv = *(const f32x4*)(noise + (size_t)b * EMB + e4 * 4);
        f32x4 r = { sa*ev[0]+sn*nv[0], sa*ev[1]+sn*nv[1], sa*ev[2]+sn*nv[2], sa*ev[3]+sn*nv[3] };
        *(f32x4*)(outb + 320 * EMB + e4 * 4) = r;
    }

    // ---- P1: rows (lane, lane+64, lane+128, lane+192): ttr/ssr/cnt + mean partials ----
    int sA[4], tA[4];
    f32x4 mean8[8];
    #pragma unroll
    for (int j = 0; j < 8; ++j) mean8[j] = f32x4{0.f, 0.f, 0.f, 0.f};
    #pragma unroll
    for (int k = 0; k < 4; ++k) {
        const int r = lane + k * 64;
        sA[k] = 1; tA[k] = MASK_T;
        if (r < LSEQ) {
            const int2 sv = ((const int2*)st)[(size_t)b * LSEQ + r];
            sA[k] = sv.x; tA[k] = sv.y;
            ttrW[r] = (unsigned short)sv.y;
            ssrW[r] = sv.x;
            if (sv.y != MASK_T) atomicAdd(&cntW[sv.y], 1.0f);
            const f32x4* lr = (const f32x4*)(loc_emb + (size_t)(sv.x - 1) * EMB);
            #pragma unroll
            for (int j = 0; j < 8; ++j) mean8[j] += lr[j];
        } else if (r < LPAD) {
            ttrW[r] = 0; ssrW[r] = 1;
        }
    }
    // 64-lane butterfly reduce (32 cols)
    #pragma unroll
    for (int s2 = 1; s2 < 64; s2 <<= 1) {
        #pragma unroll
        for (int j = 0; j < 8; ++j) {
            mean8[j][0] += __shfl_xor(mean8[j][0], s2);
            mean8[j][1] += __shfl_xor(mean8[j][1], s2);
            mean8[j][2] += __shfl_xor(mean8[j][2], s2);
            mean8[j][3] += __shfl_xor(mean8[j][3], s2);
        }
    }
    {
        f32x4* ml4 = (f32x4*)mlocW;
        if (lane == 0) ml4[0] = mean8[0];
        if (lane == 1) ml4[1] = mean8[1];
        if (lane == 2) ml4[2] = mean8[2];
        if (lane == 3) ml4[3] = mean8[3];
        if (lane == 4) ml4[4] = mean8[4];
        if (lane == 5) ml4[5] = mean8[5];
        if (lane == 6) ml4[6] = mean8[6];
        if (lane == 7) ml4[7] = mean8[7];
    }
    WAIT_LGKM();

    // ---- P2: m1[c] = b2 + (colsum@w1[:, :32]^T + cnt@T1t)/200 ----
    {
        f32x4 mm[8], cc[13];
        #pragma unroll
        for (int j = 0; j < 8; ++j)  mm[j] = ((const f32x4*)mlocW)[j];
        #pragma unroll
        for (int j = 0; j < 13; ++j) cc[j] = ((const f32x4*)cntW)[j];
        #pragma unroll
        for (int k = 0; k < 3; ++k) {
            const int c = lane + k * 64;
            if (c < COND) {
                f32x4 d = {0.f, 0.f, 0.f, 0.f};
                const f32x4* w1r = (const f32x4*)(w1 + (size_t)c * COND);
                #pragma unroll
                for (int j = 0; j < 8; ++j)  d += mm[j] * w1r[j];
                const f32x4* t1r = (const f32x4*)(T1t + c * 52);
                #pragma unroll
                for (int j = 0; j < 13; ++j) d += cc[j] * t1r[j];
                m1W[c] = b2[c] + (d[0] + d[1] + d[2] + d[3]) * 0.005f;
            }
        }
    }
    WAIT_LGKM();

    // ---- P3: register-resident B-frags (w2 cols 0..31 -> bf16) + per-tile m1/wc ----
    short8 bf[10]; float m1v[10], wcv[10];
    #pragma unroll
    for (int T = 0; T < 10; ++T) {
        const f32x4* r = (const f32x4*)(w2 + (size_t)(T * 16 + lc) * COND + lg * 8);
        bf[T]  = pack8(r[0], r[1]);
        m1v[T] = m1W[T * 16 + lc];
        wcv[T] = wc[T * 16 + lc];
    }

    // ---- P4: 13 m-tiles: MFMA(K=32) + T2 bias + sigmoid + wc-dot -> score ----
    int ssv[13];
    #pragma unroll
    for (int m = 0; m < 13; ++m) ssv[m] = ssrW[m * 16 + lc];

    #pragma unroll
    for (int m = 0; m < 13; ++m) {
        const ushort4 tq = *(const ushort4*)(ttrW + m * 16 + lg * 4);
        ushort4 t2q[4][3];
        #pragma unroll
        for (int r = 0; r < 4; ++r) {
            const int t = (r == 0) ? tq.x : (r == 1) ? tq.y : (r == 2) ? tq.z : tq.w;
            const unsigned short* t2r = T2w + t * 192 + lc * 12;
            t2q[r][0] = *(const ushort4*)(t2r);
            t2q[r][1] = *(const ushort4*)(t2r + 4);
            t2q[r][2] = *(const ushort4*)(t2r + 8);
        }
        const f32x4* ar = (const f32x4*)(loc_emb + (size_t)(ssv[m] - 1) * EMB + lg * 8);
        const short8 av = pack8(ar[0], ar[1]);

        f32x4 srow = {0.f, 0.f, 0.f, 0.f};
        #pragma unroll
        for (int T = 0; T < 10; ++T) {
            f32x4 acc = {0.f, 0.f, 0.f, 0.f};
            acc = __builtin_amdgcn_mfma_f32_16x16x32_bf16(av, bf[T], acc, 0, 0, 0);
            #pragma unroll
            for (int r = 0; r < 4; ++r) {
                const ushort4 q = t2q[r][T >> 2];
                const unsigned short t2u =
                    ((T & 3) == 0) ? q.x : ((T & 3) == 1) ? q.y : ((T & 3) == 2) ? q.z : q.w;
                const float x = acc[r] + m1v[T] + bf2f(t2u);
                srow[r] = fmaf(wcv[T], __builtin_amdgcn_rcpf(1.0f + __expf(-x)), srow[r]);
            }
        }
        srow[0] = red16(srow[0]); srow[1] = red16(srow[1]);
        srow[2] = red16(srow[2]); srow[3] = red16(srow[3]);
        if (lc == 0) *(f32x4*)(scoreW + m * 16 + lg * 4) = srow;
    }
    WAIT_LGKM();

    // ---- P5: sb histogram + uemb_loc (register partials + butterfly) ----
    f32x4 u8[8];
    #pragma unroll
    for (int j = 0; j < 8; ++j) u8[j] = f32x4{0.f, 0.f, 0.f, 0.f};
    #pragma unroll
    for (int k = 0; k < 4; ++k) {
        const int r = lane + k * 64;
        if (r < LSEQ) {
            const float sc = scoreW[r];
            if (tA[k] != MASK_T) atomicAdd(&sbW[tA[k]], sc);
            const f32x4* lr = (const f32x4*)(loc_emb + (size_t)(sA[k] - 1) * EMB);
            #pragma unroll
            for (int j = 0; j < 8; ++j) u8[j] += sc * lr[j];
        }
    }
    #pragma unroll
    for (int s2 = 1; s2 < 64; s2 <<= 1) {
        #pragma unroll
        for (int j = 0; j < 8; ++j) {
            u8[j][0] += __shfl_xor(u8[j][0], s2);
            u8[j][1] += __shfl_xor(u8[j][1], s2);
            u8[j][2] += __shfl_xor(u8[j][2], s2);
            u8[j][3] += __shfl_xor(u8[j][3], s2);
        }
    }
    {
        f32x4* ul4 = (f32x4*)(suW + 160);
        if (lane == 0) ul4[0] = u8[0];
        if (lane == 1) ul4[1] = u8[1];
        if (lane == 2) ul4[2] = u8[2];
        if (lane == 3) ul4[3] = u8[3];
        if (lane == 4) ul4[4] = u8[4];
        if (lane == 5) ul4[5] = u8[5];
        if (lane == 6) ul4[6] = u8[6];
        if (lane == 7) ul4[7] = u8[7];
    }
    WAIT_LGKM();

    // ---- P5b: uemb_te[j] = sum_t sb[t]*te[t][j] ----
    {
        f32x4 sbr[13];
        #pragma unroll
        for (int j = 0; j < 13; ++j) sbr[j] = ((const f32x4*)sbW)[j];
        #pragma unroll
        for (int k = 0; k < 2; ++k) {
            const int j = lane + k * 64;             // 0..127
            const unsigned short* ter = te_t + j * 52;
            float s = 0.0f;
            #pragma unroll
            for (int q = 0; q < 13; ++q) {
                const ushort4 tv = *(const ushort4*)(ter + q * 4);
                s = fmaf(sbr[q][0], bf2f(tv.x), s);
                s = fmaf(sbr[q][1], bf2f(tv.y), s);
                s = fmaf(sbr[q][2], bf2f(tv.z), s);
                s = fmaf(sbr[q][3], bf2f(tv.w), s);
            }
            suW[192 + j] = s;
        }
    }
    WAIT_LGKM();

    // ---- P6: broadcast-write rows 0..319 (side | uemb), coalesced f32x4 ----
    #pragma unroll 4
    for (int k = 0; k < 40; ++k) {
        const int idx = lane + k * 64;
        const int row = idx >> 3;
        const float v = suW[row];
        f32x4 vv = {v, v, v, v};
        *(f32x4*)(outb + row * EMB + (idx & 7) * 4) = vv;
    }
}

extern "C" void kernel_launch(void* const* d_in, const int* in_sizes, int n_in,
                              void* d_out, int out_size, void* d_ws, size_t ws_size,
                              hipStream_t stream) {
    const int*   tp        = (const int*)  d_in[0];
    const int*   loc       = (const int*)  d_in[1];
    const float* emb       = (const float*)d_in[2];
    const int*   st        = (const int*)  d_in[3];
    const float* loc_emb   = (const float*)d_in[4];
    const float* noise     = (const float*)d_in[5];
    const int*   tstep     = (const int*)  d_in[6];
    const float* w1        = (const float*)d_in[7];
    const float* w2        = (const float*)d_in[8];
    const float* b2        = (const float*)d_in[9];
    const float* wc        = (const float*)d_in[10];
    const float* alpha_hat = (const float*)d_in[11];
    float* out = (float*)d_out;

    char* ws = (char*)d_ws;
    float*          T1t    = (float*)ws;                          // 33,280 B
    unsigned short* te_tab = (unsigned short*)(ws + 33280);       // 12,544 B
    unsigned short* te_t   = (unsigned short*)(ws + 45824);       // 13,312 B
    unsigned short* T2w    = (unsigned short*)(ws + 59136);       // 18,816 B

    prep<<<49, 256, 0, stream>>>(w1, w2, te_tab, T1t, te_t, T2w);

    const int nb = in_sizes[0];   // 2048
    fused_wave<<<(nb + 3) / 4, 256, 0, stream>>>(tp, loc, emb, st, loc_emb, noise,
                                                 tstep, w1, w2, te_tab, T1t, te_t,
                                                 T2w, b2, wc, alpha_hat, out, nb);
}

// Round 8
// 65.638 us; speedup vs baseline: 1.5813x; 1.1552x over previous
//
#include <hip/hip_runtime.h>
#include <hip/hip_bf16.h>

#define LSEQ   200
#define LPAD   208
#define EMB    32
#define TDIM   128
#define COND   160
#define ROWS   321
#define MASK_T 48
#define LL_LDB 80      // LL row stride bytes (64B data + 16B pad)

typedef __attribute__((ext_vector_type(8))) short  short8;
typedef __attribute__((ext_vector_type(4))) float  f32x4;

__device__ __forceinline__ float bf2f(unsigned short u) {
    union { unsigned int i; float f; } v; v.i = ((unsigned int)u) << 16; return v.f;
}
__device__ __forceinline__ float asf(unsigned int u) {
    union { unsigned int i; float f; } v; v.i = u; return v.f;
}
__device__ __forceinline__ unsigned int f2bf(float f) {
    union { float f; unsigned int i; } v; v.f = f;
    unsigned int x = v.i;
    return ((x + 0x7fffu + ((x >> 16) & 1u)) >> 16);   // RNE, low 16
}
__device__ __forceinline__ unsigned int pack2(float lo, float hi) {
    return f2bf(lo) | (f2bf(hi) << 16);
}
__device__ __forceinline__ short8 pack8(f32x4 a, f32x4 b) {
    union { short8 s; unsigned int u[4]; } r;
    r.u[0] = pack2(a[0], a[1]); r.u[1] = pack2(a[2], a[3]);
    r.u[2] = pack2(b[0], b[1]); r.u[3] = pack2(b[2], b[3]);
    return r.s;
}

template<int CTRL>
__device__ __forceinline__ float dpp_add(float v) {
    const int x = __builtin_amdgcn_update_dpp(0, __float_as_int(v), CTRL, 0xf, 0xf, true);
    return v + __int_as_float(x);
}
__device__ __forceinline__ float red16(float v) {
    v = dpp_add<0x128>(v);   // row_ror:8
    v = dpp_add<0x124>(v);   // row_ror:4
    v = dpp_add<0x122>(v);   // row_ror:2
    v = dpp_add<0x121>(v);   // row_ror:1
    return v;
}

// ---- prep (49 blocks): te_tab[49][128] bf16; T1t[160][52] f32; te_t[128][52] bf16;
//      T2w2[49][2][16][8] bf16: T2w2[t][wg][lc][Tp] = T2[t][(5*wg+Tp)*16+lc]; row t==48 -> 0.
__global__ void prep(const float* __restrict__ w1, const float* __restrict__ w2,
                     unsigned short* __restrict__ te_tab, float* __restrict__ T1t,
                     unsigned short* __restrict__ te_t, unsigned short* __restrict__ T2w2) {
    __shared__ float te128[TDIM];
    const int t = blockIdx.x, tid = threadIdx.x;
    if (tid < 64) {
        const float dv = __expf(-0.14391156f * (float)tid);  // 10000^(-tid/64)
        const float a  = (float)t * dv;
        const float s  = __sinf(a), c = __cosf(a);
        te128[2 * tid] = s; te128[2 * tid + 1] = c;
        ((unsigned int*)te_tab)[t * 64 + tid] = pack2(s, c);
    }
    __syncthreads();
    if (tid < COND) {
        float s1 = 0.0f, s2 = 0.0f;
        const float* w1r = w1 + tid * COND + EMB;
        const float* w2r = w2 + tid * COND + EMB;
        #pragma unroll 8
        for (int j = 0; j < TDIM; ++j) {
            s1 = fmaf(te128[j], w1r[j], s1);
            s2 = fmaf(te128[j], w2r[j], s2);
        }
        if (t == MASK_T) { s1 = 0.0f; s2 = 0.0f; }
        T1t[tid * 52 + t] = s1;
        const int tile = tid >> 4, lcc = tid & 15;
        const int wg = (tile >= 5) ? 1 : 0, Tp = tile - 5 * wg;
        T2w2[t * 256 + wg * 128 + lcc * 8 + Tp] = (unsigned short)f2bf(s2);
    }
    if (tid < TDIM) te_t[tid * 52 + t] = (unsigned short)f2bf(te128[tid]);
}

// ---- main: one batch per 128-thread block (2 waves), n-split GEMM ----
__global__ __launch_bounds__(128, 4)
void fused2(const int*   __restrict__ tp,
            const int*   __restrict__ loc,
            const float* __restrict__ emb,
            const int*   __restrict__ st,        // [B][L][2]
            const float* __restrict__ loc_emb,   // [V][32] fp32
            const float* __restrict__ noise,
            const int*   __restrict__ tstep,
            const float* __restrict__ w1,        // fp32 (cols 0..31 used)
            const float* __restrict__ w2,        // fp32 (cols 0..31 used)
            const unsigned short* __restrict__ te_tab,
            const float* __restrict__ T1t,       // [160][52]
            const unsigned short* __restrict__ te_t,   // [128][52]
            const unsigned short* __restrict__ T2w2,   // [49][2][16][8]
            const float* __restrict__ b2,
            const float* __restrict__ wc,
            const float* __restrict__ alpha_hat,
            float* __restrict__ out)             // [B][321][32]
{
    __shared__ __attribute__((aligned(16))) unsigned char LL[LPAD * LL_LDB]; // 16,640
    __shared__ float scoreW[LSEQ];            // 800
    __shared__ float su[320];                 // 1,280  [side(160) | uemb(160)]
    __shared__ float m1W[COND];               // 640
    __shared__ float mupart[2][EMB];          // 256  (mean partials, then uemb partials)
    __shared__ float cntsb[52];               // 208  (cnt, then sb histogram)
    __shared__ __attribute__((aligned(8))) unsigned short ttr[LPAD];  // 416

    const int tid  = threadIdx.x;
    const int w    = tid >> 6, lane = tid & 63;
    const int b    = blockIdx.x;
    const int lc   = lane & 15, lg = lane >> 4;
    const int rsub = lane >> 3, csub = lane & 7;
    const int2* st2 = (const int2*)st;
    float* outb = out + (size_t)b * (ROWS * EMB);

    // ---- P0: side row, noisy row, zero-init ----
    if (w == 0) {
        if (lane < 32) {
            const ushort4 tv = *(const ushort4*)(te_tab + tp[b] * TDIM + lane * 4);
            f32x4 s4 = { bf2f(tv.x), bf2f(tv.y), bf2f(tv.z), bf2f(tv.w) };
            *(f32x4*)(su + lane * 4) = s4;
        } else if (lane < 40) {
            *(f32x4*)(su + 128 + (lane - 32) * 4) =
                *(const f32x4*)(loc_emb + (size_t)(loc[b] - 1) * EMB + (lane - 32) * 4);
        } else if (lane < 48) {
            const int e4 = lane - 40;
            const float a  = alpha_hat[tstep[b]];
            const float sa = sqrtf(a), sn = sqrtf(1.0f - a);
            const f32x4 ev = *(const f32x4*)(emb + (size_t)b * EMB + e4 * 4);
            const f32x4 nv = *(const f32x4*)(noise + (size_t)b * EMB + e4 * 4);
            f32x4 r = { sa*ev[0]+sn*nv[0], sa*ev[1]+sn*nv[1],
                        sa*ev[2]+sn*nv[2], sa*ev[3]+sn*nv[3] };
            *(f32x4*)(outb + 320 * EMB + e4 * 4) = r;
        }
    } else {
        if (lane < 52) cntsb[lane] = 0.0f;
        if (lane < 50) {
            f32x4 z = {0.f, 0.f, 0.f, 0.f};
            *(f32x4*)(scoreW + lane * 4) = z;
        }
        if (lane >= 52 && lane < 60) {               // zero-pad rows 200..207
            const int r = 200 + lane - 52;
            uint4 z = make_uint4(0, 0, 0, 0);
            *(uint4*)(LL + r * LL_LDB)      = z;
            *(uint4*)(LL + r * LL_LDB + 16) = z;
            *(uint4*)(LL + r * LL_LDB + 32) = z;
            *(uint4*)(LL + r * LL_LDB + 48) = z;
            ttr[r] = 0;
        }
    }
    __syncthreads();   // B0

    // ---- P1a: ttr + cnt histogram (wave w owns rows w*100..w*100+99) ----
    int tA0, tA1 = MASK_T;
    {
        const int r = w * 100 + lane;
        const int2 sv = st2[(size_t)b * LSEQ + r];
        ttr[r] = (unsigned short)sv.y;
        tA0 = sv.y;
        if (sv.y != MASK_T) atomicAdd(&cntsb[sv.y], 1.0f);
        if (lane < 36) {
            const int r2 = r + 64;
            const int2 sv2 = st2[(size_t)b * LSEQ + r2];
            ttr[r2] = (unsigned short)sv2.y;
            tA1 = sv2.y;
            if (sv2.y != MASK_T) atomicAdd(&cntsb[sv2.y], 1.0f);
        }
    }

    // ---- P1b: quarter-row gather -> LL(bf16) + mean partials ----
    f32x4 macc = {0.f, 0.f, 0.f, 0.f};
    #pragma unroll
    for (int i = 0; i < 13; ++i) {
        const int rr = i * 8 + rsub;
        if (rr < 100) {
            const int row = w * 100 + rr;
            const int s0 = st2[(size_t)b * LSEQ + row].x - 1;
            const f32x4 v = *(const f32x4*)(loc_emb + (size_t)s0 * EMB + csub * 4);
            macc += v;
            uint2 pv = make_uint2(pack2(v[0], v[1]), pack2(v[2], v[3]));
            *(uint2*)(LL + row * LL_LDB + csub * 8) = pv;
        }
    }
    #pragma unroll
    for (int sh = 8; sh < 64; sh <<= 1) {
        macc[0] += __shfl_xor(macc[0], sh);
        macc[1] += __shfl_xor(macc[1], sh);
        macc[2] += __shfl_xor(macc[2], sh);
        macc[3] += __shfl_xor(macc[3], sh);
    }
    if (rsub == 0) *(f32x4*)(&mupart[w][csub * 4]) = macc;
    __syncthreads();   // B1

    // ---- P2: m1[c] = b2 + (colsum@w1[:, :32]^T + cnt@T1t)/200 ----
    {
        f32x4 mm[8];
        #pragma unroll
        for (int j = 0; j < 8; ++j)
            mm[j] = ((const f32x4*)mupart[0])[j] + ((const f32x4*)mupart[1])[j];
        #pragma unroll
        for (int k = 0; k < 2; ++k) {
            const int c = tid + k * 128;
            if (c < COND) {
                f32x4 d = {0.f, 0.f, 0.f, 0.f};
                const f32x4* w1r = (const f32x4*)(w1 + (size_t)c * COND);
                #pragma unroll
                for (int j = 0; j < 8; ++j) d += mm[j] * w1r[j];
                const f32x4* t1r = (const f32x4*)(T1t + c * 52);
                #pragma unroll
                for (int q = 0; q < 13; ++q)
                    d += ((const f32x4*)cntsb)[q] * t1r[q];
                m1W[c] = b2[c] + (d[0] + d[1] + d[2] + d[3]) * 0.005f;
            }
        }
    }
    __syncthreads();   // B2

    if (w == 1 && lane < 52) cntsb[lane] = 0.0f;   // re-zero as sb (read after B3)

    // ---- P3: this wave's 5 B-frags (w2 rows -> bf16) + per-tile m1/wc ----
    short8 bf[5]; float m1v[5], wcv[5];
    #pragma unroll
    for (int T = 0; T < 5; ++T) {
        const int c = (5 * w + T) * 16 + lc;
        const f32x4* r = (const f32x4*)(w2 + (size_t)c * COND + lg * 8);
        bf[T]  = pack8(r[0], r[1]);
        m1v[T] = m1W[c];
        wcv[T] = wc[c];
    }

    // ---- P4: 13 m-tiles x 5 n-tiles: MFMA(K=32) + T2 bias + sigmoid -> score ----
    for (int m = 0; m < 13; ++m) {
        const short8 av = *(const short8*)(LL + (m * 16 + lc) * LL_LDB + lg * 16);
        const ushort4 tq = *(const ushort4*)(ttr + m * 16 + lg * 4);
        ushort4 q0[4], q1[4];
        #pragma unroll
        for (int r = 0; r < 4; ++r) {
            const int t = (r == 0) ? tq.x : (r == 1) ? tq.y : (r == 2) ? tq.z : tq.w;
            const unsigned short* p = T2w2 + t * 256 + w * 128 + lc * 8;
            q0[r] = *(const ushort4*)(p);
            q1[r] = *(const ushort4*)(p + 4);
        }
        f32x4 srow = {0.f, 0.f, 0.f, 0.f};
        #pragma unroll
        for (int T = 0; T < 5; ++T) {
            f32x4 acc = {0.f, 0.f, 0.f, 0.f};
            acc = __builtin_amdgcn_mfma_f32_16x16x32_bf16(av, bf[T], acc, 0, 0, 0);
            #pragma unroll
            for (int r = 0; r < 4; ++r) {
                const unsigned short t2u =
                    (T == 0) ? q0[r].x : (T == 1) ? q0[r].y :
                    (T == 2) ? q0[r].z : (T == 3) ? q0[r].w : q1[r].x;
                const float x = acc[r] + m1v[T] + bf2f(t2u);
                srow[r] = fmaf(wcv[T], __builtin_amdgcn_rcpf(1.0f + __expf(-x)), srow[r]);
            }
        }
        srow[0] = red16(srow[0]); srow[1] = red16(srow[1]);
        srow[2] = red16(srow[2]); srow[3] = red16(srow[3]);
        if (lc == 0) {
            #pragma unroll
            for (int r = 0; r < 4; ++r) {
                const int row = m * 16 + lg * 4 + r;
                if (row < LSEQ) atomicAdd(&scoreW[row], srow[r]);
            }
        }
    }
    __syncthreads();   // B3

    // ---- P5a: sb histogram ----
    {
        const int r = w * 100 + lane;
        const float sc = scoreW[r];
        if (tA0 != MASK_T) atomicAdd(&cntsb[tA0], sc);
        if (lane < 36) {
            const float sc2 = scoreW[r + 64];
            if (tA1 != MASK_T) atomicAdd(&cntsb[tA1], sc2);
        }
    }
    // ---- P5: uemb_loc quarter-row partials from LL ----
    f32x4 uacc = {0.f, 0.f, 0.f, 0.f};
    #pragma unroll
    for (int i = 0; i < 13; ++i) {
        const int rr = i * 8 + rsub;
        if (rr < 100) {
            const int row = w * 100 + rr;
            const float sc = scoreW[row];
            const uint2 pv = *(const uint2*)(LL + row * LL_LDB + csub * 8);
            uacc[0] = fmaf(sc, asf(pv.x << 16), uacc[0]);
            uacc[1] = fmaf(sc, asf(pv.x & 0xffff0000u), uacc[1]);
            uacc[2] = fmaf(sc, asf(pv.y << 16), uacc[2]);
            uacc[3] = fmaf(sc, asf(pv.y & 0xffff0000u), uacc[3]);
        }
    }
    #pragma unroll
    for (int sh = 8; sh < 64; sh <<= 1) {
        uacc[0] += __shfl_xor(uacc[0], sh);
        uacc[1] += __shfl_xor(uacc[1], sh);
        uacc[2] += __shfl_xor(uacc[2], sh);
        uacc[3] += __shfl_xor(uacc[3], sh);
    }
    if (rsub == 0) *(f32x4*)(&mupart[w][csub * 4]) = uacc;
    __syncthreads();   // B4

    // ---- P5b: uemb_te[j] = sum_t sb[t]*te_t[j][t]; combine uemb_loc ----
    {
        const int j = tid;                               // 0..127
        const unsigned short* ter = te_t + j * 52;
        float s = 0.0f;
        #pragma unroll
        for (int q = 0; q < 13; ++q) {
            const f32x4 sq = ((const f32x4*)cntsb)[q];
            const ushort4 tv = *(const ushort4*)(ter + q * 4);
            s = fmaf(sq[0], bf2f(tv.x), s);
            s = fmaf(sq[1], bf2f(tv.y), s);
            s = fmaf(sq[2], bf2f(tv.z), s);
            s = fmaf(sq[3], bf2f(tv.w), s);
        }
        su[192 + j] = s;
    }
    if (tid < 32) su[160 + tid] = mupart[0][tid] + mupart[1][tid];
    __syncthreads();   // B5

    // ---- P6: broadcast-write rows 0..319 ----
    #pragma unroll
    for (int k = 0; k < 20; ++k) {
        const int idx = tid + k * 128;
        const int row = idx >> 3;
        const float v = su[row];
        f32x4 vv = {v, v, v, v};
        *(f32x4*)(outb + row * EMB + (idx & 7) * 4) = vv;
    }
}

extern "C" void kernel_launch(void* const* d_in, const int* in_sizes, int n_in,
                              void* d_out, int out_size, void* d_ws, size_t ws_size,
                              hipStream_t stream) {
    const int*   tp        = (const int*)  d_in[0];
    const int*   loc       = (const int*)  d_in[1];
    const float* emb       = (const float*)d_in[2];
    const int*   st        = (const int*)  d_in[3];
    const float* loc_emb   = (const float*)d_in[4];
    const float* noise     = (const float*)d_in[5];
    const int*   tstep     = (const int*)  d_in[6];
    const float* w1        = (const float*)d_in[7];
    const float* w2        = (const float*)d_in[8];
    const float* b2        = (const float*)d_in[9];
    const float* wc        = (const float*)d_in[10];
    const float* alpha_hat = (const float*)d_in[11];
    float* out = (float*)d_out;

    char* ws = (char*)d_ws;
    float*          T1t    = (float*)ws;                          // 33,280 B
    unsigned short* te_tab = (unsigned short*)(ws + 33280);       // 12,544 B
    unsigned short* te_t   = (unsigned short*)(ws + 45824);       // 13,312 B
    unsigned short* T2w2   = (unsigned short*)(ws + 59136);       // 25,088 B

    prep<<<49, 256, 0, stream>>>(w1, w2, te_tab, T1t, te_t, T2w2);

    const int nb = in_sizes[0];   // 2048
    fused2<<<nb, 128, 0, stream>>>(tp, loc, emb, st, loc_emb, noise, tstep,
                                   w1, w2, te_tab, T1t, te_t, T2w2,
                                   b2, wc, alpha_hat, out);
}